// Round 7
// baseline (858.916 us; speedup 1.0000x reference)
//
#include <hip/hip_runtime.h>
#include <hip/hip_bf16.h>
#include <stdint.h>

#define SQ 2048
#define DK 64
#define NB 32
#define TQ 16
#define KH 1024            // k-half per block
#define NTHREADS 512
#define SCL 0.18033688011112042f   // log2(e)/8

typedef __attribute__((ext_vector_type(8))) short short8;
typedef __attribute__((ext_vector_type(4))) float f32x4;
typedef __attribute__((ext_vector_type(4))) unsigned u32x4;
typedef __attribute__((ext_vector_type(2))) unsigned u32x2;

// ---- bf16 helpers (RNE) ----
__device__ __forceinline__ unsigned f2bf_u(float x) {
    unsigned u = __builtin_bit_cast(unsigned, x);
    u += 0x7fffu + ((u >> 16) & 1u);
    return u >> 16;
}
__device__ __forceinline__ float bf2f(unsigned h) {
    return __builtin_bit_cast(float, h << 16);
}
__device__ __forceinline__ float bf2f_hi(unsigned u) {
    return __builtin_bit_cast(float, u & 0xffff0000u);
}
__device__ __forceinline__ void split8(const float* p, short8& h, short8& l) {
    f32x4 a = *(const f32x4*)p;
    f32x4 b = *(const f32x4*)(p + 4);
    #pragma unroll
    for (int j = 0; j < 4; ++j) {
        unsigned ua = f2bf_u(a[j]);
        h[j] = (short)ua; l[j] = (short)f2bf_u(a[j] - bf2f(ua));
        unsigned ub = f2bf_u(b[j]);
        h[j + 4] = (short)ub; l[j + 4] = (short)f2bf_u(b[j] - bf2f(ub));
    }
}

// ============ prep: K -> bf16 hi/lo planes; V -> transposed bf16 plane ============
__global__ __launch_bounds__(256) void prep_kernel(
    const float* __restrict__ K, const float* __restrict__ V,
    unsigned short* __restrict__ Khi, unsigned short* __restrict__ Klo,
    unsigned short* __restrict__ Vt)
{
    __shared__ float vtile[64][65];
    const int t  = threadIdx.x;
    const int b  = blockIdx.x >> 5;
    const int s0 = (blockIdx.x & 31) << 6;
    const size_t base = ((size_t)b * SQ + s0) * DK + (size_t)t * 16;

    {
        short8 h0, l0, h1, l1;
        split8(K + base,     h0, l0);
        split8(K + base + 8, h1, l1);
        *(short8*)(Khi + base)     = h0;
        *(short8*)(Khi + base + 8) = h1;
        *(short8*)(Klo + base)     = l0;
        *(short8*)(Klo + base + 8) = l1;
    }
    {
        const int sr = t >> 2, dc = (t & 3) << 4;
        #pragma unroll
        for (int u = 0; u < 16; u += 4) {
            f32x4 v = *(const f32x4*)(V + base + u);
            vtile[sr][dc + u + 0] = v[0];
            vtile[sr][dc + u + 1] = v[1];
            vtile[sr][dc + u + 2] = v[2];
            vtile[sr][dc + u + 3] = v[3];
        }
    }
    __syncthreads();
    #pragma unroll
    for (int rep = 0; rep < 16; ++rep) {
        const int idx = rep * 256 + t;
        const int d = idx >> 6, s = idx & 63;
        Vt[((size_t)b * DK + d) * SQ + s0 + s] = (unsigned short)f2bf_u(vtile[s][d]);
    }
}

// ============ main fused kernel: one block = q-tile x k-half ============
__global__ __launch_bounds__(NTHREADS, 8) void sdpa_main(
    const float* __restrict__ Q, const unsigned short* __restrict__ Khi,
    const unsigned short* __restrict__ Klo, const unsigned short* __restrict__ Vt,
    const unsigned* __restrict__ Mk, float* __restrict__ Yp, float* __restrict__ Aout)
{
    __shared__ __align__(16) unsigned short e_half[TQ][KH];  // 32 KB, masked-e bf16
    __shared__ float yp[4][TQ][16];                          // 4 KB
    __shared__ float rsum[8][TQ];                            // 512 B
    __shared__ float i2s[TQ];

    const int tid  = threadIdx.x;
    const int lane = tid & 63;
    const int wv   = tid >> 6;
    const int m16  = lane & 15;
    const int kq   = lane >> 4;
    const int koff = kq * 8;

    const int bx = blockIdx.x;
    const int b  = bx >> 8;
    const int qt = (bx >> 1) & 127;
    const int kh = bx & 1;
    const int q0 = qt * TQ;
    const int wlocal = wv & 3;                 // strip index within own half
    const bool owned = (wv >> 2) == kh;        // does this wave's strip fall in our half?

    // Q fragments (B-operand), split bf16
    short8 qh[2], ql[2];
    {
        const float* qrow = Q + ((size_t)b * SQ + q0 + m16) * DK;
        split8(qrow + koff,      qh[0], ql[0]);
        split8(qrow + 32 + koff, qh[1], ql[1]);
    }

    // ---- Phase A: full-k rowsum; owned strips also mask+pack -> LDS ----
    // wave wv computes global k-strip [wv*256, wv*256+256)
    float rs = 0.f;
    {
        const size_t krow = ((size_t)b * SQ + wv * 256 + m16) * DK;
        const unsigned short* khp = Khi + krow;
        const unsigned short* klp = Klo + krow;
        const int xw = (m16 & 7) << 3;

        if (owned) {
            const unsigned* mrow = Mk + ((size_t)b * SQ + q0 + m16) * SQ
                                 + (size_t)kh * KH + wlocal * 256 + kq * 4;
            for (int t = 0; t < 16; ++t) {
                const int off = t * 16 * DK;
                f32x4 acc = {0.f, 0.f, 0.f, 0.f};
                #pragma unroll
                for (int c = 0; c < 2; ++c) {
                    short8 k_h = *(const short8*)(khp + off + c * 32 + koff);
                    short8 k_l = *(const short8*)(klp + off + c * 32 + koff);
                    acc = __builtin_amdgcn_mfma_f32_16x16x32_bf16(k_h, qh[c], acc, 0, 0, 0);
                    acc = __builtin_amdgcn_mfma_f32_16x16x32_bf16(k_h, ql[c], acc, 0, 0, 0);
                    acc = __builtin_amdgcn_mfma_f32_16x16x32_bf16(k_l, qh[c], acc, 0, 0, 0);
                }
                const u32x4 m = __builtin_nontemporal_load((const u32x4*)(mrow + t * 16));
                const float e0 = exp2f(acc[0] * SCL);
                const float e1 = exp2f(acc[1] * SCL);
                const float e2 = exp2f(acc[2] * SCL);
                const float e3 = exp2f(acc[3] * SCL);
                rs += (e0 + e1) + (e2 + e3);
                const float a0 = m[0] ? e0 : 0.f;
                const float a1 = m[1] ? e1 : 0.f;
                const float a2 = m[2] ? e2 : 0.f;
                const float a3 = m[3] ? e3 : 0.f;
                u32x2 pk;
                pk[0] = f2bf_u(a0) | (f2bf_u(a1) << 16);
                pk[1] = f2bf_u(a2) | (f2bf_u(a3) << 16);
                *(u32x2*)&e_half[m16][(wlocal * 256 + t * 16 + kq * 4) ^ xw] = pk;
            }
        } else {
            for (int t = 0; t < 16; ++t) {
                const int off = t * 16 * DK;
                f32x4 acc = {0.f, 0.f, 0.f, 0.f};
                #pragma unroll
                for (int c = 0; c < 2; ++c) {
                    short8 k_h = *(const short8*)(khp + off + c * 32 + koff);
                    short8 k_l = *(const short8*)(klp + off + c * 32 + koff);
                    acc = __builtin_amdgcn_mfma_f32_16x16x32_bf16(k_h, qh[c], acc, 0, 0, 0);
                    acc = __builtin_amdgcn_mfma_f32_16x16x32_bf16(k_h, ql[c], acc, 0, 0, 0);
                    acc = __builtin_amdgcn_mfma_f32_16x16x32_bf16(k_l, qh[c], acc, 0, 0, 0);
                }
                rs += (exp2f(acc[0] * SCL) + exp2f(acc[1] * SCL))
                    + (exp2f(acc[2] * SCL) + exp2f(acc[3] * SCL));
            }
        }
    }
    rs += __shfl_xor(rs, 16);
    rs += __shfl_xor(rs, 32);
    if (lane < 16) rsum[wv][lane] = rs;
    __syncthreads();
    if (tid < 16) {
        float s = 0.f;
        #pragma unroll
        for (int w = 0; w < 8; ++w) s += rsum[w][tid];
        i2s[tid] = 2.0f / s;       // includes dropout keep-scale
    }
    __syncthreads();

    // ---- CD phase (barrier-free): attn store + PV over our k-half ----
    const int cr = tid >> 5;            // C row (0..15)
    const int cc = (tid & 31) * 8;      // C col base within 256-stripe
    const int xc = (cr & 7) << 3;
    const float i2 = i2s[cr];
    const size_t arow = ((size_t)b * SQ + q0 + cr) * SQ + (size_t)kh * KH + cc;

    const int g   = wv >> 1;            // d-group 0..3
    const int par = wv & 1;             // k-parity within half
    const int xm  = (m16 & 7) << 3;
    const unsigned short* vbase = Vt + ((size_t)b * DK + g * 16 + m16) * SQ + (size_t)kh * KH;
    f32x4 acc = {0.f, 0.f, 0.f, 0.f};

    #define CSTRIPE(s)                                                            \
    {                                                                             \
        const u32x4 ev = *(const u32x4*)&e_half[cr][((s) * 256 + cc) ^ xc];       \
        f32x4 o0, o1;                                                             \
        o0[0] = bf2f(ev[0] & 0xffffu) * i2;  o0[1] = bf2f_hi(ev[0]) * i2;         \
        o0[2] = bf2f(ev[1] & 0xffffu) * i2;  o0[3] = bf2f_hi(ev[1]) * i2;         \
        o1[0] = bf2f(ev[2] & 0xffffu) * i2;  o1[1] = bf2f_hi(ev[2]) * i2;         \
        o1[2] = bf2f(ev[3] & 0xffffu) * i2;  o1[3] = bf2f_hi(ev[3]) * i2;         \
        __builtin_nontemporal_store(o0, (f32x4*)(Aout + arow + (s) * 256));       \
        __builtin_nontemporal_store(o1, (f32x4*)(Aout + arow + (s) * 256 + 4));   \
    }
    #define PVCHUNK4(c0)                                                          \
    {                                                                             \
        _Pragma("unroll")                                                         \
        for (int c = (c0); c < (c0) + 4; ++c) {                                   \
            const int kl = par * 512 + c * 32;                                    \
            short8 af = *(const short8*)&e_half[m16][(kl + koff) ^ xm];           \
            short8 vf = *(const short8*)(vbase + kl + koff);                      \
            acc = __builtin_amdgcn_mfma_f32_16x16x32_bf16(af, vf, acc, 0, 0, 0);  \
        }                                                                         \
    }

    CSTRIPE(0) PVCHUNK4(0)
    CSTRIPE(1) PVCHUNK4(4)
    CSTRIPE(2) PVCHUNK4(8)
    CSTRIPE(3) PVCHUNK4(12)

    #undef PVCHUNK4
    #undef CSTRIPE

    // ---- combine k-parities, normalize, write y-partial for this half ----
    if (par == 1) {
        #pragma unroll
        for (int r = 0; r < 4; ++r) yp[g][kq * 4 + r][m16] = acc[r];
    }
    __syncthreads();
    if (par == 0) {
        #pragma unroll
        for (int r = 0; r < 4; ++r) {
            const float yv = (acc[r] + yp[g][kq * 4 + r][m16]) * i2s[kq * 4 + r];
            Yp[((size_t)(kh * NB + b) * SQ + q0 + kq * 4 + r) * DK + g * 16 + m16] = yv;
        }
    }
}

// ============ y reduction: sum the two k-half partials ============
__global__ __launch_bounds__(256) void yred_kernel(
    const float* __restrict__ Yp, float* __restrict__ Yout)
{
    const size_t NEL = (size_t)NB * SQ * DK;
    const size_t i = ((size_t)blockIdx.x * 256 + threadIdx.x) * 4;
    f32x4 a = *(const f32x4*)(Yp + i);
    f32x4 b = *(const f32x4*)(Yp + NEL + i);
    f32x4 s = a + b;
    __builtin_nontemporal_store(s, (f32x4*)(Yout + i));
}

extern "C" void kernel_launch(void* const* d_in, const int* in_sizes, int n_in,
                              void* d_out, int out_size, void* d_ws, size_t ws_size,
                              hipStream_t stream) {
    const float*    Q  = (const float*)d_in[0];
    const float*    K  = (const float*)d_in[1];
    const float*    V  = (const float*)d_in[2];
    const unsigned* Mk = (const unsigned*)d_in[3];
    float* Yout = (float*)d_out;
    float* Aout = (float*)d_out + (size_t)NB * SQ * DK;

    const size_t NEL = (size_t)NB * SQ * DK;
    unsigned short* Khi = (unsigned short*)d_ws;
    unsigned short* Klo = Khi + NEL;
    unsigned short* Vt  = Klo + NEL;
    float*          Yp  = (float*)(Vt + NEL);   // 2 * NEL floats

    prep_kernel<<<dim3(NB * (SQ / 64)), dim3(256), 0, stream>>>(K, V, Khi, Klo, Vt);
    sdpa_main<<<dim3(NB * 128 * 2), dim3(NTHREADS), 0, stream>>>(
        Q, Khi, Klo, Vt, Mk, Yp, Aout);
    yred_kernel<<<dim3((unsigned)(NEL / 1024)), dim3(256), 0, stream>>>(Yp, Yout);
}

// Round 8
// 523.873 us; speedup vs baseline: 1.6396x; 1.6396x over previous
//
#include <hip/hip_runtime.h>
#include <hip/hip_bf16.h>
#include <stdint.h>

#define SQ 2048
#define DK 64
#define NB 32
#define TQ 16
#define EW 2064            // bf16 elems per LDS score row
#define NTHREADS 512
#define SCL 0.18033688011112042f   // log2(e)/8

typedef __attribute__((ext_vector_type(8))) short short8;
typedef __attribute__((ext_vector_type(4))) float f32x4;
typedef __attribute__((ext_vector_type(4))) unsigned u32x4;
typedef __attribute__((ext_vector_type(2))) unsigned u32x2;

// ---- bf16 helpers (RNE) ----
__device__ __forceinline__ unsigned f2bf_u(float x) {
    unsigned u = __builtin_bit_cast(unsigned, x);
    u += 0x7fffu + ((u >> 16) & 1u);
    return u >> 16;
}
__device__ __forceinline__ float bf2f(unsigned h) {
    return __builtin_bit_cast(float, h << 16);
}
__device__ __forceinline__ float bf2f_hi(unsigned u) {
    return __builtin_bit_cast(float, u & 0xffff0000u);
}
__device__ __forceinline__ void split8(const float* p, short8& h, short8& l) {
    f32x4 a = *(const f32x4*)p;
    f32x4 b = *(const f32x4*)(p + 4);
    #pragma unroll
    for (int j = 0; j < 4; ++j) {
        unsigned ua = f2bf_u(a[j]);
        h[j] = (short)ua; l[j] = (short)f2bf_u(a[j] - bf2f(ua));
        unsigned ub = f2bf_u(b[j]);
        h[j + 4] = (short)ub; l[j + 4] = (short)f2bf_u(b[j] - bf2f(ub));
    }
}

// ============ prep: K -> bf16 hi/lo planes; V -> transposed bf16 plane ============
__global__ __launch_bounds__(256) void prep_kernel(
    const float* __restrict__ K, const float* __restrict__ V,
    unsigned short* __restrict__ Khi, unsigned short* __restrict__ Klo,
    unsigned short* __restrict__ Vt)
{
    __shared__ float vtile[64][65];
    const int t  = threadIdx.x;
    const int b  = blockIdx.x >> 5;
    const int s0 = (blockIdx.x & 31) << 6;
    const size_t base = ((size_t)b * SQ + s0) * DK + (size_t)t * 16;

    {
        short8 h0, l0, h1, l1;
        split8(K + base,     h0, l0);
        split8(K + base + 8, h1, l1);
        *(short8*)(Khi + base)     = h0;
        *(short8*)(Khi + base + 8) = h1;
        *(short8*)(Klo + base)     = l0;
        *(short8*)(Klo + base + 8) = l1;
    }
    {
        const int sr = t >> 2, dc = (t & 3) << 4;
        #pragma unroll
        for (int u = 0; u < 16; u += 4) {
            f32x4 v = *(const f32x4*)(V + base + u);
            vtile[sr][dc + u + 0] = v[0];
            vtile[sr][dc + u + 1] = v[1];
            vtile[sr][dc + u + 2] = v[2];
            vtile[sr][dc + u + 3] = v[3];
        }
    }
    __syncthreads();
    #pragma unroll
    for (int rep = 0; rep < 16; ++rep) {
        const int idx = rep * 256 + t;
        const int d = idx >> 6, s = idx & 63;
        Vt[((size_t)b * DK + d) * SQ + s0 + s] = (unsigned short)f2bf_u(vtile[s][d]);
    }
}

// ============ main fused kernel ============
__global__ __launch_bounds__(NTHREADS, 4) void sdpa_main(
    const float* __restrict__ Q, const unsigned short* __restrict__ Khi,
    const unsigned short* __restrict__ Klo, const unsigned short* __restrict__ Vt,
    const unsigned* __restrict__ Mk, float* __restrict__ Yout, float* __restrict__ Aout)
{
    __shared__ __align__(16) unsigned short e_lds[TQ][EW];  // 66048 B, masked-e bf16
    __shared__ float yp[4][TQ][16];
    __shared__ float rsum[8][TQ];
    __shared__ float i2s[TQ];

    const int tid  = threadIdx.x;
    const int lane = tid & 63;
    const int wv   = tid >> 6;
    const int m16  = lane & 15;
    const int kq   = lane >> 4;
    const int koff = kq * 8;

    // XCD batch-affinity swizzle: XCD x owns batches 4x..4x+3
    const int bx = blockIdx.x;
    const int xcd = bx & 7;
    const int j   = bx >> 3;
    const int b   = xcd * 4 + (j >> 7);
    const int q0  = (j & 127) * TQ;

    // Q fragments (B-operand), split bf16
    short8 qh[2], ql[2];
    {
        const float* qrow = Q + ((size_t)b * SQ + q0 + m16) * DK;
        split8(qrow + koff,      qh[0], ql[0]);
        split8(qrow + 32 + koff, qh[1], ql[1]);
    }

    // ---- Phase A: masked-e = mask * exp(QK^T/8) -> bf16 LDS; rowsum of unmasked e ----
    float rs = 0.f;
    {
        const size_t krow = ((size_t)b * SQ + wv * 256 + m16) * DK;
        const unsigned short* khp = Khi + krow;
        const unsigned short* klp = Klo + krow;
        const unsigned* mrow = Mk + ((size_t)b * SQ + q0 + m16) * SQ + wv * 256 + kq * 4;
        const int xw = (m16 & 7) << 3;

        #define KDEF(t) short8 kh0_##t, kh1_##t, kl0_##t, kl1_##t;
        #define KLOAD(t) {                                                        \
            const int off = (t) * 16 * DK;                                        \
            kh0_##t = *(const short8*)(khp + off + koff);                         \
            kh1_##t = *(const short8*)(khp + off + 32 + koff);                    \
            kl0_##t = *(const short8*)(klp + off + koff);                         \
            kl1_##t = *(const short8*)(klp + off + 32 + koff); }
        #define MDEF(t) u32x4 m_##t;
        #define MLOAD(t) m_##t = __builtin_nontemporal_load((const u32x4*)(mrow + (t) * 16));
        #define AITER(t) {                                                        \
            f32x4 acc = {0.f, 0.f, 0.f, 0.f};                                     \
            acc = __builtin_amdgcn_mfma_f32_16x16x32_bf16(kh0_##t, qh[0], acc, 0, 0, 0); \
            acc = __builtin_amdgcn_mfma_f32_16x16x32_bf16(kh0_##t, ql[0], acc, 0, 0, 0); \
            acc = __builtin_amdgcn_mfma_f32_16x16x32_bf16(kl0_##t, qh[0], acc, 0, 0, 0); \
            acc = __builtin_amdgcn_mfma_f32_16x16x32_bf16(kh1_##t, qh[1], acc, 0, 0, 0); \
            acc = __builtin_amdgcn_mfma_f32_16x16x32_bf16(kh1_##t, ql[1], acc, 0, 0, 0); \
            acc = __builtin_amdgcn_mfma_f32_16x16x32_bf16(kl1_##t, qh[1], acc, 0, 0, 0); \
            const float e0 = __builtin_amdgcn_exp2f(acc[0] * SCL);                \
            const float e1 = __builtin_amdgcn_exp2f(acc[1] * SCL);                \
            const float e2 = __builtin_amdgcn_exp2f(acc[2] * SCL);                \
            const float e3 = __builtin_amdgcn_exp2f(acc[3] * SCL);                \
            rs += (e0 + e1) + (e2 + e3);                                          \
            const float a0 = m_##t[0] ? e0 : 0.f;                                 \
            const float a1 = m_##t[1] ? e1 : 0.f;                                 \
            const float a2 = m_##t[2] ? e2 : 0.f;                                 \
            const float a3 = m_##t[3] ? e3 : 0.f;                                 \
            u32x2 pk;                                                             \
            pk[0] = f2bf_u(a0) | (f2bf_u(a1) << 16);                              \
            pk[1] = f2bf_u(a2) | (f2bf_u(a3) << 16);                              \
            *(u32x2*)&e_lds[m16][(wv * 256 + (t) * 16 + kq * 4) ^ xw] = pk; }

        KDEF(0)  KDEF(1)  KDEF(2)  KDEF(3)  KDEF(4)  KDEF(5)  KDEF(6)  KDEF(7)
        KDEF(8)  KDEF(9)  KDEF(10) KDEF(11) KDEF(12) KDEF(13) KDEF(14) KDEF(15)
        MDEF(0)  MDEF(1)  MDEF(2)  MDEF(3)  MDEF(4)  MDEF(5)  MDEF(6)  MDEF(7)
        MDEF(8)  MDEF(9)  MDEF(10) MDEF(11) MDEF(12) MDEF(13) MDEF(14) MDEF(15)

        KLOAD(0)  KLOAD(1)
        MLOAD(0)  MLOAD(1)  MLOAD(2)  MLOAD(3)
        KLOAD(2)  MLOAD(4)   AITER(0)
        KLOAD(3)  MLOAD(5)   AITER(1)
        KLOAD(4)  MLOAD(6)   AITER(2)
        KLOAD(5)  MLOAD(7)   AITER(3)
        KLOAD(6)  MLOAD(8)   AITER(4)
        KLOAD(7)  MLOAD(9)   AITER(5)
        KLOAD(8)  MLOAD(10)  AITER(6)
        KLOAD(9)  MLOAD(11)  AITER(7)
        KLOAD(10) MLOAD(12)  AITER(8)
        KLOAD(11) MLOAD(13)  AITER(9)
        KLOAD(12) MLOAD(14)  AITER(10)
        KLOAD(13) MLOAD(15)  AITER(11)
        KLOAD(14)            AITER(12)
        KLOAD(15)            AITER(13)
                             AITER(14)
                             AITER(15)

        #undef AITER
        #undef MLOAD
        #undef MDEF
        #undef KLOAD
        #undef KDEF
    }
    rs += __shfl_xor(rs, 16);
    rs += __shfl_xor(rs, 32);
    if (lane < 16) rsum[wv][lane] = rs;
    __syncthreads();
    if (tid < 16) {
        float s = 0.f;
        #pragma unroll
        for (int w = 0; w < 8; ++w) s += rsum[w][tid];
        i2s[tid] = 2.0f / s;       // includes dropout keep-scale
    }
    __syncthreads();

    // ---- CD phase (barrier-free): attn store + PV with Vt prefetch ----
    const int cr = tid >> 5;
    const int cc = (tid & 31) * 8;
    const int xc = (cr & 7) << 3;
    const float i2 = i2s[cr];
    const size_t crow = ((size_t)b * SQ + q0 + cr) * SQ + cc;

    const int g    = wv >> 1;           // d-group 0..3
    const int parh = (wv & 1) * 128;    // k-parity offset within stripe
    const int xm   = (m16 & 7) << 3;
    const unsigned short* vrow = Vt + ((size_t)b * DK + g * 16 + m16) * SQ;
    f32x4 acc = {0.f, 0.f, 0.f, 0.f};

    #define CSTRIPE(s)                                                            \
    {                                                                             \
        const u32x4 ev = *(const u32x4*)&e_lds[cr][((s) * 256 + cc) ^ xc];        \
        f32x4 o0, o1;                                                             \
        o0[0] = bf2f(ev[0] & 0xffffu) * i2;  o0[1] = bf2f_hi(ev[0]) * i2;         \
        o0[2] = bf2f(ev[1] & 0xffffu) * i2;  o0[3] = bf2f_hi(ev[1]) * i2;         \
        o1[0] = bf2f(ev[2] & 0xffffu) * i2;  o1[1] = bf2f_hi(ev[2]) * i2;         \
        o1[2] = bf2f(ev[3] & 0xffffu) * i2;  o1[3] = bf2f_hi(ev[3]) * i2;         \
        __builtin_nontemporal_store(o0, (f32x4*)(Aout + crow + (s) * 256));       \
        __builtin_nontemporal_store(o1, (f32x4*)(Aout + crow + (s) * 256 + 4));   \
    }
    #define VDEF(u) short8 vf_##u;
    #define VLOAD(u) vf_##u = *(const short8*)(vrow + ((u) >> 2) * 256 + parh + ((u) & 3) * 32 + koff);
    #define PV1(u) {                                                              \
        const int k0 = ((u) >> 2) * 256 + parh + ((u) & 3) * 32;                  \
        short8 af = *(const short8*)&e_lds[m16][(k0 + koff) ^ xm];                \
        acc = __builtin_amdgcn_mfma_f32_16x16x32_bf16(af, vf_##u, acc, 0, 0, 0); }

    VDEF(0)  VDEF(1)  VDEF(2)  VDEF(3)  VDEF(4)  VDEF(5)  VDEF(6)  VDEF(7)
    VDEF(8)  VDEF(9)  VDEF(10) VDEF(11) VDEF(12) VDEF(13) VDEF(14) VDEF(15)
    VDEF(16) VDEF(17) VDEF(18) VDEF(19) VDEF(20) VDEF(21) VDEF(22) VDEF(23)
    VDEF(24) VDEF(25) VDEF(26) VDEF(27) VDEF(28) VDEF(29) VDEF(30) VDEF(31)

    VLOAD(0) VLOAD(1) VLOAD(2) VLOAD(3)
    CSTRIPE(0)
    PV1(0)  VLOAD(4)  PV1(1)  VLOAD(5)  PV1(2)  VLOAD(6)  PV1(3)  VLOAD(7)
    CSTRIPE(1)
    PV1(4)  VLOAD(8)  PV1(5)  VLOAD(9)  PV1(6)  VLOAD(10) PV1(7)  VLOAD(11)
    CSTRIPE(2)
    PV1(8)  VLOAD(12) PV1(9)  VLOAD(13) PV1(10) VLOAD(14) PV1(11) VLOAD(15)
    CSTRIPE(3)
    PV1(12) VLOAD(16) PV1(13) VLOAD(17) PV1(14) VLOAD(18) PV1(15) VLOAD(19)
    CSTRIPE(4)
    PV1(16) VLOAD(20) PV1(17) VLOAD(21) PV1(18) VLOAD(22) PV1(19) VLOAD(23)
    CSTRIPE(5)
    PV1(20) VLOAD(24) PV1(21) VLOAD(25) PV1(22) VLOAD(26) PV1(23) VLOAD(27)
    CSTRIPE(6)
    PV1(24) VLOAD(28) PV1(25) VLOAD(29) PV1(26) VLOAD(30) PV1(27) VLOAD(31)
    CSTRIPE(7)
    PV1(28) PV1(29) PV1(30) PV1(31)

    #undef PV1
    #undef VLOAD
    #undef VDEF
    #undef CSTRIPE

    // ---- combine k-parities, normalize, write y ----
    if ((wv & 1) == 1) {
        #pragma unroll
        for (int r = 0; r < 4; ++r) yp[g][kq * 4 + r][m16] = acc[r];
    }
    __syncthreads();
    if ((wv & 1) == 0) {
        #pragma unroll
        for (int r = 0; r < 4; ++r) {
            const float yv = (acc[r] + yp[g][kq * 4 + r][m16]) * i2s[kq * 4 + r];
            __builtin_nontemporal_store(yv,
                Yout + ((size_t)b * SQ + q0 + kq * 4 + r) * DK + g * 16 + m16);
        }
    }
}

extern "C" void kernel_launch(void* const* d_in, const int* in_sizes, int n_in,
                              void* d_out, int out_size, void* d_ws, size_t ws_size,
                              hipStream_t stream) {
    const float*    Q  = (const float*)d_in[0];
    const float*    K  = (const float*)d_in[1];
    const float*    V  = (const float*)d_in[2];
    const unsigned* Mk = (const unsigned*)d_in[3];
    float* Yout = (float*)d_out;
    float* Aout = (float*)d_out + (size_t)NB * SQ * DK;

    const size_t NEL = (size_t)NB * SQ * DK;
    unsigned short* Khi = (unsigned short*)d_ws;
    unsigned short* Klo = Khi + NEL;
    unsigned short* Vt  = Klo + NEL;

    prep_kernel<<<dim3(NB * (SQ / 64)), dim3(256), 0, stream>>>(K, V, Khi, Klo, Vt);
    sdpa_main<<<dim3(NB * (SQ / TQ)), dim3(NTHREADS), 0, stream>>>(
        Q, Khi, Klo, Vt, Mk, Yout, Aout);
}